// Round 1
// baseline (620.340 us; speedup 1.0000x reference)
//
#include <hip/hip_runtime.h>
#include <math.h>

// Problem constants
#define BB 4
#define TT 32
#define HH 160
#define WW 320
#define NF 8
#define FPF 8
#define SDIM 8
#define UU 64
#define SS 72            // NF*FPF + SDIM
#define UNFOLDS 6

__device__ __forceinline__ float fast_sigmoid(float x) {
    // sigmoid(x) = 1 / (1 + 2^(-x*log2(e)))
    float e = exp2f(-1.44269504f * x);
    return __builtin_amdgcn_rcpf(1.0f + e);
}

// ---------------- weight transpose: [oc][ic][5][5] -> [ic*25+j][oc] ----------------
__global__ void transpose_w_kernel(const float* __restrict__ w, float* __restrict__ wt,
                                   int OC, int IC) {
    int i = blockIdx.x * 256 + threadIdx.x;
    int total = OC * IC * 25;
    if (i >= total) return;
    int oc = i % OC;
    int rest = i / OC;
    int j = rest % 25;
    int ic = rest / 25;
    wt[i] = w[(oc * IC + ic) * 25 + j];
}

// ---------------- direct 5x5 stride-2 pad-2 conv + relu ----------------
// one thread computes all OC channels for one (n, oy, ox)
template <int IC, int OC>
__global__ __launch_bounds__(256) void conv5x5_kernel(
    const float* __restrict__ in, const float* __restrict__ wt,
    const float* __restrict__ bias, float* __restrict__ out,
    int N, int IH, int IW, int OH, int OW) {
    int idx = blockIdx.x * 256 + threadIdx.x;
    int total = N * OH * OW;
    if (idx >= total) return;
    int ox = idx % OW;
    int r = idx / OW;
    int oy = r % OH;
    int n = r / OH;

    float acc[OC];
#pragma unroll
    for (int o = 0; o < OC; o++) acc[o] = bias[o];

    int iy0 = oy * 2 - 2;
    int ix0 = ox * 2 - 2;
    const float* inb = in + (size_t)n * IC * IH * IW;
    for (int ic = 0; ic < IC; ic++) {
        const float* inc = inb + (size_t)ic * IH * IW;
#pragma unroll
        for (int ky = 0; ky < 5; ky++) {
            int iy = iy0 + ky;
            if (iy < 0 || iy >= IH) continue;
            const float* row = inc + (size_t)iy * IW;
#pragma unroll
            for (int kx = 0; kx < 5; kx++) {
                int ix = ix0 + kx;
                float x = (ix >= 0 && ix < IW) ? row[ix] : 0.0f;
                const float* wp = wt + (ic * 25 + ky * 5 + kx) * OC;
#pragma unroll
                for (int o = 0; o < OC; o++) acc[o] = fmaf(x, wp[o], acc[o]);
            }
        }
    }
    size_t ohw = (size_t)OH * OW;
    size_t obase = (size_t)n * OC * ohw + (size_t)oy * OW + ox;
#pragma unroll
    for (int o = 0; o < OC; o++) out[obase + o * ohw] = fmaxf(acc[o], 0.0f);
}

// ---------------- head: feats[n, f*8+k] = sum_p x[n,f,p] * hw[f,p,k] + hb[f,k] ----------------
__global__ void head_kernel(const float* __restrict__ x, const float* __restrict__ hw,
                            const float* __restrict__ hb, float* __restrict__ feats) {
    int n = blockIdx.x;      // 0..127  (n = b*32 + t)
    int tid = threadIdx.x;   // 0..63
    int f = tid >> 3;
    int k = tid & 7;
    const float* xb = x + (size_t)n * NF * 800 + (size_t)f * 800;
    const float* wb = hw + (size_t)f * 800 * FPF + k;
    float acc = hb[tid];
    for (int p = 0; p < 800; p++) acc = fmaf(xb[p], wb[(size_t)p * FPF], acc);
    feats[n * 64 + tid] = acc;
}

// ---------------- global std (ddof=1) over 8192 feats -> invstd ----------------
__global__ void stats_kernel(const float* __restrict__ feats, float* __restrict__ invstd) {
    __shared__ float s_sum[256], s_sq[256];
    int tid = threadIdx.x;
    float s = 0.0f, q = 0.0f;
    for (int i = tid; i < 8192; i += 256) {
        float x = feats[i];
        s += x;
        q += x * x;
    }
    s_sum[tid] = s;
    s_sq[tid] = q;
    __syncthreads();
    for (int off = 128; off > 0; off >>= 1) {
        if (tid < off) {
            s_sum[tid] += s_sum[tid + off];
            s_sq[tid] += s_sq[tid + off];
        }
        __syncthreads();
    }
    if (tid == 0) {
        float mean = s_sum[0] / 8192.0f;
        float var = (s_sq[0] - 8192.0f * mean * mean) / 8191.0f;
        var = fmaxf(var, 0.0f);
        invstd[0] = 1.0f / (sqrtf(var) + 1e-5f);
    }
}

// ---------------- speed embedding: tanh(relu(s*W1+b1)*W2+b2) ----------------
__global__ void semb_kernel(const float* __restrict__ speed, const float* __restrict__ w1,
                            const float* __restrict__ b1, const float* __restrict__ w2,
                            const float* __restrict__ b2, float* __restrict__ emb) {
    int n = threadIdx.x;  // 0..127  (n = b*32 + t)
    float s = speed[n];
    float h[16];
#pragma unroll
    for (int j = 0; j < 16; j++) h[j] = fmaxf(fmaf(s, w1[j], b1[j]), 0.0f);
#pragma unroll
    for (int k = 0; k < SDIM; k++) {
        float a = b2[k];
#pragma unroll
        for (int j = 0; j < 16; j++) a = fmaf(h[j], w2[j * SDIM + k], a);
        emb[n * SDIM + k] = tanhf(a);
    }
}

// ---------------- sensory precompute: w_num_s / w_den_s for all (t,b,u) ----------------
__global__ void sensory_kernel(const float* __restrict__ feats, const float* __restrict__ emb,
                               const float* __restrict__ invstd, const float* __restrict__ inw,
                               const float* __restrict__ inb, const float* __restrict__ ssig,
                               const float* __restrict__ smu, const float* __restrict__ sw,
                               const float* __restrict__ serev, float* __restrict__ wns,
                               float* __restrict__ wds) {
    int bid = blockIdx.x;    // t*4 + b
    int t = bid >> 2;
    int b = bid & 3;
    int u = threadIdx.x;     // 0..63
    int n = b * TT + t;
    float inv = invstd[0];
    float num = 0.0f, den = 0.0f;
    for (int s = 0; s < SS; s++) {
        float xsv = (s < 64) ? feats[n * 64 + s] * inv : emb[n * SDIM + (s - 64)];
        float inp = fmaf(xsv, inw[s], inb[s]);
        int idx = s * UU + u;
        float x = (inp - smu[idx]) * ssig[idx];
        float act = sw[idx] * fast_sigmoid(x);
        num = fmaf(act, serev[idx], num);
        den += act;
    }
    wns[bid * UU + u] = num;
    wds[bid * UU + u] = den;
}

// ---------------- LTC scan: 4 blocks (one per batch), 256 threads ----------------
// thread = pc*?? no: tid = pc*64 + u ; pc = pre-chunk (0..3), u = post unit
__global__ __launch_bounds__(256) void scan_kernel(
    const float* __restrict__ wns, const float* __restrict__ wds,
    const float* __restrict__ gleak, const float* __restrict__ vleak,
    const float* __restrict__ cm, const float* __restrict__ sigma,
    const float* __restrict__ mu, const float* __restrict__ wsyn,
    const float* __restrict__ erev, const float* __restrict__ outw,
    const float* __restrict__ outb, float* __restrict__ dout) {
    int b = blockIdx.x;
    int tid = threadIdx.x;
    int u = tid & 63;
    int pc = tid >> 6;  // 0..3

    __shared__ float vsh[64];
    __shared__ float pn[4][64], pd[4][64];

    // preload this thread's 16 pre-synapse parameter rows into registers
    float p_sig[16], p_mu[16], p_w[16], p_er[16];
#pragma unroll
    for (int i = 0; i < 16; i++) {
        int pre = pc * 16 + i;
        p_sig[i] = sigma[pre * UU + u];
        p_mu[i] = mu[pre * UU + u];
        p_w[i] = wsyn[pre * UU + u];
        p_er[i] = erev[pre * UU + u];
    }
    float cmt = cm[u] * (float)UNFOLDS;
    float gl = gleak[u];
    float glvl = gl * vleak[u];
    float v_u = 0.0f;
    if (tid < 64) vsh[u] = 0.0f;
    __syncthreads();

    for (int t = 0; t < TT; t++) {
        float num_s = wns[(t * BB + b) * UU + u];
        float den_s = wds[(t * BB + b) * UU + u];
        for (int k = 0; k < UNFOLDS; k++) {
            float num = 0.0f, den = 0.0f;
#pragma unroll
            for (int i = 0; i < 16; i++) {
                float x = (vsh[pc * 16 + i] - p_mu[i]) * p_sig[i];
                float a = p_w[i] * fast_sigmoid(x);
                num = fmaf(a, p_er[i], num);
                den += a;
            }
            pn[pc][u] = num;
            pd[pc][u] = den;
            __syncthreads();
            if (tid < 64) {
                float nn = pn[0][u] + pn[1][u] + pn[2][u] + pn[3][u] + num_s;
                float dd = pd[0][u] + pd[1][u] + pd[2][u] + pd[3][u] + den_s;
                v_u = (cmt * v_u + glvl + nn) / (cmt + gl + dd + 1e-8f);
                vsh[u] = v_u;
            }
            __syncthreads();
        }
        if (tid < 64) {
            // all_h: offset 128+256=384, layout (B,T,U)
            dout[384 + (b * TT + t) * UU + u] = v_u;
            if (u == 0) dout[b * TT + t] = fmaf(v_u, outw[0], outb[0]);  // readout (B,T,1)
            if (t == TT - 1) dout[128 + b * UU + u] = v_u;               // v_last (B,U)
        }
    }
}

extern "C" void kernel_launch(void* const* d_in, const int* in_sizes, int n_in,
                              void* d_out, int out_size, void* d_ws, size_t ws_size,
                              hipStream_t stream) {
    const float* in_seq = (const float*)d_in[0];
    const float* speed = (const float*)d_in[1];
    const float* c1w = (const float*)d_in[2];
    const float* c1b = (const float*)d_in[3];
    const float* c2w = (const float*)d_in[4];
    const float* c2b = (const float*)d_in[5];
    const float* c3w = (const float*)d_in[6];
    const float* c3b = (const float*)d_in[7];
    const float* hw = (const float*)d_in[8];
    const float* hb = (const float*)d_in[9];
    const float* sew1 = (const float*)d_in[10];
    const float* seb1 = (const float*)d_in[11];
    const float* sew2 = (const float*)d_in[12];
    const float* seb2 = (const float*)d_in[13];
    const float* inw = (const float*)d_in[14];
    const float* inb = (const float*)d_in[15];
    const float* gleak = (const float*)d_in[16];
    const float* vleak = (const float*)d_in[17];
    const float* cm = (const float*)d_in[18];
    const float* sigma = (const float*)d_in[19];
    const float* mu = (const float*)d_in[20];
    const float* wsyn = (const float*)d_in[21];
    const float* erev = (const float*)d_in[22];
    const float* ssig = (const float*)d_in[23];
    const float* smu = (const float*)d_in[24];
    const float* sw = (const float*)d_in[25];
    const float* serev = (const float*)d_in[26];
    const float* outw = (const float*)d_in[27];
    const float* outb = (const float*)d_in[28];

    float* ws = (float*)d_ws;
    float* out = (float*)d_out;

    // workspace layout (floats)
    size_t o_c1 = 0;                                   // conv1 out: 128*16*80*160
    size_t o_c2 = o_c1 + (size_t)128 * 16 * 80 * 160;  // conv2 out: 128*32*40*80
    size_t o_c3 = o_c2 + (size_t)128 * 32 * 40 * 80;   // conv3 out: 128*8*800
    size_t o_ft = o_c3 + (size_t)128 * 8 * 800;        // feats: 128*64
    size_t o_emb = o_ft + 8192;                        // emb: 128*8
    size_t o_inv = o_emb + 1024;                       // invstd: 1 (pad 16)
    size_t o_wns = o_inv + 16;                         // wns: 128*64
    size_t o_wds = o_wns + 8192;                       // wds: 128*64
    size_t o_w1 = o_wds + 8192;                        // wt1: 1200
    size_t o_w2 = o_w1 + 1200;                         // wt2: 12800
    size_t o_w3 = o_w2 + 12800;                        // wt3: 6400

    float* c1out = ws + o_c1;
    float* c2out = ws + o_c2;
    float* c3out = ws + o_c3;
    float* feats = ws + o_ft;
    float* emb = ws + o_emb;
    float* invstd = ws + o_inv;
    float* wns = ws + o_wns;
    float* wds = ws + o_wds;
    float* wt1 = ws + o_w1;
    float* wt2 = ws + o_w2;
    float* wt3 = ws + o_w3;

    // weight transposes
    transpose_w_kernel<<<(16 * 3 * 25 + 255) / 256, 256, 0, stream>>>(c1w, wt1, 16, 3);
    transpose_w_kernel<<<(32 * 16 * 25 + 255) / 256, 256, 0, stream>>>(c2w, wt2, 32, 16);
    transpose_w_kernel<<<(8 * 32 * 25 + 255) / 256, 256, 0, stream>>>(c3w, wt3, 8, 32);

    // convs
    conv5x5_kernel<3, 16><<<(128 * 80 * 160) / 256, 256, 0, stream>>>(
        in_seq, wt1, c1b, c1out, 128, 160, 320, 80, 160);
    conv5x5_kernel<16, 32><<<(128 * 40 * 80) / 256, 256, 0, stream>>>(
        c1out, wt2, c2b, c2out, 128, 80, 160, 40, 80);
    conv5x5_kernel<32, 8><<<(128 * 20 * 40) / 256, 256, 0, stream>>>(
        c2out, wt3, c3b, c3out, 128, 40, 80, 20, 40);

    // head + stats + speed embedding
    head_kernel<<<128, 64, 0, stream>>>(c3out, hw, hb, feats);
    stats_kernel<<<1, 256, 0, stream>>>(feats, invstd);
    semb_kernel<<<1, 128, 0, stream>>>(speed, sew1, seb1, sew2, seb2, emb);

    // sensory precompute (parallel over t,b)
    sensory_kernel<<<TT * BB, 64, 0, stream>>>(feats, emb, invstd, inw, inb, ssig, smu, sw,
                                               serev, wns, wds);

    // serial LTC scan, one block per batch
    scan_kernel<<<BB, 256, 0, stream>>>(wns, wds, gleak, vleak, cm, sigma, mu, wsyn, erev,
                                        outw, outb, out);
}